// Round 1
// baseline (312.173 us; speedup 1.0000x reference)
//
#include <hip/hip_runtime.h>

#define DEVINL __device__ __forceinline__

typedef __attribute__((ext_vector_type(8))) __bf16 bf16x8;
typedef __attribute__((ext_vector_type(4))) __bf16 bf16x4;
typedef __attribute__((ext_vector_type(4))) float f32x4;

// D = A(16x32) * B(32x16) + C, bf16 inputs, fp32 accum.
// A: m=lane&15, k=(lane>>4)*8+j ; B: n=lane&15, k=(lane>>4)*8+j
// C/D: col=lane&15, row=(lane>>4)*4+reg   [m89/m120-verified]
DEVINL f32x4 mfma16(bf16x8 a, bf16x8 b, f32x4 c) {
  return __builtin_amdgcn_mfma_f32_16x16x32_bf16(a, b, c, 0, 0, 0);
}

// Fragment of W^T: value[j] = W[kb+j][n]  (W stored (in,out), row-major 128x128)
DEVINL bf16x8 loadWfrag(const float* __restrict__ W, int kb, int n) {
  bf16x8 f;
#pragma unroll
  for (int j = 0; j < 8; ++j) f[j] = (__bf16)W[(kb + j) * 128 + n];
  return f;
}

// ---------------------------------------------------------------------------
// Kernel A: per (seq, 512-token chunk): K,V,Q projections (bf16 MFMA),
// elu+1 on K,Q; Q -> global ws (bf16, token-major); K^T,V^T -> LDS;
// KtV (per-head 32x32) + ksum accumulated, atomicAdd to ws.
// ---------------------------------------------------------------------------
__global__ __launch_bounds__(256, 2)
void qkv_ktv_kernel(const float* __restrict__ X,
                    const float* __restrict__ Wq, const float* __restrict__ bq,
                    const float* __restrict__ Wk, const float* __restrict__ bk,
                    const float* __restrict__ Wv, const float* __restrict__ bv,
                    __bf16* __restrict__ Qout,
                    float* __restrict__ ktvWs, float* __restrict__ ksumWs)
{
  __shared__ __bf16 Xs[64 * 136];   // [tok][e], pad 8 -> 2-way bank alias only
  __shared__ __bf16 Kt[128 * 72];   // [e][tok] (transposed), pad 8
  __shared__ __bf16 Vt[128 * 72];

  const int tid  = threadIdx.x;
  const int lane = tid & 63;
  const int w    = tid >> 6;       // wave 0..3 (= head for KtV)
  const int l15  = lane & 15;
  const int quad = lane >> 4;      // 0..3
  const int s     = blockIdx.x >> 2;   // sequence 0..127
  const int chunk = blockIdx.x & 3;    // 512-token chunk
  const int tokc0 = chunk * 512;
  const float* Xseq = X + (size_t)s * 2048 * 128;

  // Register-resident weight fragments. Wave w owns out-dims [32w, 32w+32).
  bf16x8 wkF[2][4], wvF[2][4], wqF[2][4];
#pragma unroll
  for (int nt = 0; nt < 2; ++nt) {
    const int n = w * 32 + nt * 16 + l15;
#pragma unroll
    for (int kk = 0; kk < 4; ++kk) {
      const int kb = kk * 32 + quad * 8;
      wkF[nt][kk] = loadWfrag(Wk, kb, n);
      wvF[nt][kk] = loadWfrag(Wv, kb, n);
      wqF[nt][kk] = loadWfrag(Wq, kb, n);  // used as A-operand (orientation 2)
    }
  }
  float bkr[2], bvr[2], bqr[2][4];
#pragma unroll
  for (int nt = 0; nt < 2; ++nt) {
    bkr[nt] = bk[w * 32 + nt * 16 + l15];
    bvr[nt] = bv[w * 32 + nt * 16 + l15];
#pragma unroll
    for (int r = 0; r < 4; ++r)
      bqr[nt][r] = bq[w * 32 + nt * 16 + quad * 4 + r];
  }

  f32x4 accT[2][2] = {};          // per-head KtV accumulators [dt][et]
  float ksumAcc[2] = {0.f, 0.f};  // per-lane partial ksum (fixed e per nt)

  for (int t = 0; t < 8; ++t) {
    const float* Xtile = Xseq + (size_t)(tokc0 + t * 64) * 128;
    __syncthreads();  // previous iter fully consumed Xs/Kt/Vt
    // --- stage X tile (fp32 global -> bf16 LDS), coalesced float4 ---
#pragma unroll
    for (int i = 0; i < 8; ++i) {
      const int flat = tid + i * 256;          // 2048 float4-chunks
      const int row = flat >> 5;
      const int c4  = (flat & 31) * 4;
      const float4 v = *(const float4*)(Xtile + row * 128 + c4);
      bf16x4 b4;
      b4[0] = (__bf16)v.x; b4[1] = (__bf16)v.y;
      b4[2] = (__bf16)v.z; b4[3] = (__bf16)v.w;
      *(bf16x4*)(&Xs[row * 136 + c4]) = b4;
    }
    __syncthreads();

    // --- K & V projections, orientation 1: D[tok][e] = X @ W ---
#pragma unroll
    for (int mt = 0; mt < 4; ++mt) {
      f32x4 aK[2] = {}, aV[2] = {};
#pragma unroll
      for (int kk = 0; kk < 4; ++kk) {
        const bf16x8 ax = *(const bf16x8*)(&Xs[(mt * 16 + l15) * 136 + kk * 32 + quad * 8]);
        aK[0] = mfma16(ax, wkF[0][kk], aK[0]);
        aK[1] = mfma16(ax, wkF[1][kk], aK[1]);
        aV[0] = mfma16(ax, wvF[0][kk], aV[0]);
        aV[1] = mfma16(ax, wvF[1][kk], aV[1]);
      }
      // epilogue: bias (+ elu+1 for K); write transposed to Kt/Vt.
      // lane holds 4 consecutive tokens at fixed e -> contiguous b64 store.
#pragma unroll
      for (int nt = 0; nt < 2; ++nt) {
        const int e    = w * 32 + nt * 16 + l15;
        const int tokb = mt * 16 + quad * 4;
        bf16x4 kq, vq;
        float ks = 0.f;
#pragma unroll
        for (int r = 0; r < 4; ++r) {
          float kv = aK[nt][r] + bkr[nt];
          kv = (kv > 0.f) ? (kv + 1.f) : __expf(kv);   // elu(x)+1
          ks += kv;
          kq[r] = (__bf16)kv;
          vq[r] = (__bf16)(aV[nt][r] + bvr[nt]);
        }
        ksumAcc[nt] += ks;
        *(bf16x4*)(&Kt[e * 72 + tokb]) = kq;
        *(bf16x4*)(&Vt[e * 72 + tokb]) = vq;
      }
    }

    // --- Q projection, orientation 2: D[e][tok] = W^T @ X^T ---
    // C/D lane holds 4 consecutive e at fixed token -> contiguous global store.
#pragma unroll
    for (int ntq = 0; ntq < 4; ++ntq) {
      f32x4 aQ[2] = {};
#pragma unroll
      for (int kk = 0; kk < 4; ++kk) {
        const bf16x8 bx = *(const bf16x8*)(&Xs[(ntq * 16 + l15) * 136 + kk * 32 + quad * 8]);
        aQ[0] = mfma16(wqF[0][kk], bx, aQ[0]);
        aQ[1] = mfma16(wqF[1][kk], bx, aQ[1]);
      }
      const int tok = tokc0 + t * 64 + ntq * 16 + l15;
      __bf16* qrow = Qout + ((size_t)s * 2048 + tok) * 128;
#pragma unroll
      for (int mt = 0; mt < 2; ++mt) {
        bf16x4 qq;
#pragma unroll
        for (int r = 0; r < 4; ++r) {
          float qv = aQ[mt][r] + bqr[mt][r];
          qv = (qv > 0.f) ? (qv + 1.f) : __expf(qv);
          qq[r] = (__bf16)qv;
        }
        *(bf16x4*)(qrow + w * 32 + mt * 16 + quad * 4) = qq;
      }
    }
    __syncthreads();

    // --- KtV: wave w = head w. D[d][e] += K_h^T(32 x tok) @ V_h(tok x 32) ---
    // Wave reads only the Kt/Vt rows it wrote itself (e in [32w,32w+32)).
#pragma unroll
    for (int kk = 0; kk < 2; ++kk) {
      bf16x8 aF[2], bF[2];
#pragma unroll
      for (int dt = 0; dt < 2; ++dt)
        aF[dt] = *(const bf16x8*)(&Kt[(w * 32 + dt * 16 + l15) * 72 + kk * 32 + quad * 8]);
#pragma unroll
      for (int et = 0; et < 2; ++et)
        bF[et] = *(const bf16x8*)(&Vt[(w * 32 + et * 16 + l15) * 72 + kk * 32 + quad * 8]);
#pragma unroll
      for (int dt = 0; dt < 2; ++dt)
#pragma unroll
        for (int et = 0; et < 2; ++et)
          accT[dt][et] = mfma16(aF[dt], bF[et], accT[dt][et]);
    }
  }

  // --- flush partials: ktv[s][h][d][e], ksum[s][e] (fp32 atomics) ---
  float* ktvH = ktvWs + ((size_t)s * 4 + w) * 1024;
#pragma unroll
  for (int dt = 0; dt < 2; ++dt)
#pragma unroll
    for (int et = 0; et < 2; ++et)
#pragma unroll
      for (int r = 0; r < 4; ++r)
        atomicAdd(&ktvH[(dt * 16 + quad * 4 + r) * 32 + et * 16 + l15], accT[dt][et][r]);

#pragma unroll
  for (int nt = 0; nt < 2; ++nt) {
    float v2 = ksumAcc[nt];
    v2 += __shfl_down(v2, 32);
    v2 += __shfl_down(v2, 16);
    if (quad == 0)
      atomicAdd(&ksumWs[s * 128 + w * 32 + nt * 16 + l15], v2);
  }
}

// ---------------------------------------------------------------------------
// Kernel B: per (seq, 512-token chunk): Z = 1/(q.ksum+eps); per-head
// A2 = (q @ KtV_h) * Z (block-diagonal collapse: wave w = head w, single
// K-step); out = A2 @ Wo + bo (fp32).
// ---------------------------------------------------------------------------
__global__ __launch_bounds__(256, 2)
void attn_out_kernel(const __bf16* __restrict__ Qin,
                     const float* __restrict__ ktvWs, const float* __restrict__ ksumWs,
                     const float* __restrict__ Wo, const float* __restrict__ bo,
                     float* __restrict__ Out)
{
  __shared__ __bf16 Qs[64 * 136];
  __shared__ __bf16 A2s[64 * 136];
  __shared__ float ksums[128];
  __shared__ float Zs[64 * 4];

  const int tid  = threadIdx.x;
  const int lane = tid & 63;
  const int w    = tid >> 6;   // wave = head
  const int l15  = lane & 15;
  const int quad = lane >> 4;
  const int s     = blockIdx.x >> 2;
  const int chunk = blockIdx.x & 3;

  if (tid < 128) ksums[tid] = ksumWs[s * 128 + tid];

  // KtV_h as orientation-2 A-fragments: A[e'][d] = KtV[h][d][e']
  const float* ktvH = ktvWs + ((size_t)s * 4 + w) * 1024;
  bf16x8 aKtv[2];
#pragma unroll
  for (int mt = 0; mt < 2; ++mt)
#pragma unroll
    for (int j = 0; j < 8; ++j)
      aKtv[mt][j] = (__bf16)ktvH[(quad * 8 + j) * 32 + mt * 16 + l15];

  bf16x8 woF[2][4];
  float bor[2];
#pragma unroll
  for (int nt = 0; nt < 2; ++nt) {
    const int n = w * 32 + nt * 16 + l15;
    bor[nt] = bo[n];
#pragma unroll
    for (int kk = 0; kk < 4; ++kk)
      woF[nt][kk] = loadWfrag(Wo, kk * 32 + quad * 8, n);
  }
  __syncthreads();

  for (int t = 0; t < 8; ++t) {
    const int tok0 = chunk * 512 + t * 64;
    const __bf16* Qtile = Qin + ((size_t)s * 2048 + tok0) * 128;
    __syncthreads();  // previous iter done with Qs/A2s
#pragma unroll
    for (int i = 0; i < 4; ++i) {
      const int c = tid + i * 256;       // 1024 16B-chunks
      const int row = c >> 4, cc = (c & 15) * 8;
      *(bf16x8*)(&Qs[row * 136 + cc]) = *(const bf16x8*)(Qtile + row * 128 + cc);
    }
    __syncthreads();
    // --- Z: one (token, head) per thread ---
    {
      const int tok = tid >> 2, h = tid & 3;
      float dot = 0.f;
      const __bf16* qrow = &Qs[tok * 136 + h * 32];
      const float* ksrow = &ksums[h * 32];
#pragma unroll
      for (int j = 0; j < 32; ++j) dot += (float)qrow[j] * ksrow[j];
      Zs[tok * 4 + h] = 1.f / (dot + 1e-6f);
    }
    __syncthreads();
    // --- GEMM2 (orientation 2): D[e'][tok] = KtV_h^T-frag @ Q^T, then *Z ---
#pragma unroll
    for (int ntq = 0; ntq < 4; ++ntq) {
      const bf16x8 bq8 = *(const bf16x8*)(&Qs[(ntq * 16 + l15) * 136 + w * 32 + quad * 8]);
      f32x4 acc[2] = {};
      acc[0] = mfma16(aKtv[0], bq8, acc[0]);
      acc[1] = mfma16(aKtv[1], bq8, acc[1]);
      const int tokRow = ntq * 16 + l15;
      const float z = Zs[tokRow * 4 + w];
#pragma unroll
      for (int mt = 0; mt < 2; ++mt) {
        bf16x4 a4;
#pragma unroll
        for (int r = 0; r < 4; ++r) a4[r] = (__bf16)(acc[mt][r] * z);
        *(bf16x4*)(&A2s[tokRow * 136 + w * 32 + mt * 16 + quad * 4]) = a4;
      }
    }
    __syncthreads();
    // --- GEMM3 (orientation 1): out[tok][n] = A2 @ Wo + bo ---
#pragma unroll
    for (int mt = 0; mt < 4; ++mt) {
      f32x4 acc[2] = {};
#pragma unroll
      for (int kk = 0; kk < 4; ++kk) {
        const bf16x8 aa = *(const bf16x8*)(&A2s[(mt * 16 + l15) * 136 + kk * 32 + quad * 8]);
        acc[0] = mfma16(aa, woF[0][kk], acc[0]);
        acc[1] = mfma16(aa, woF[1][kk], acc[1]);
      }
      const int tokb = tok0 + mt * 16 + quad * 4;
      float* orow = Out + ((size_t)s * 2048 + tokb) * 128;
#pragma unroll
      for (int nt = 0; nt < 2; ++nt) {
        const int n = w * 32 + nt * 16 + l15;
#pragma unroll
        for (int r = 0; r < 4; ++r)
          orow[(size_t)r * 128 + n] = acc[nt][r] + bor[nt];
      }
    }
  }
}

extern "C" void kernel_launch(void* const* d_in, const int* in_sizes, int n_in,
                              void* d_out, int out_size, void* d_ws, size_t ws_size,
                              hipStream_t stream) {
  const float* X  = (const float*)d_in[0];
  const float* Wq = (const float*)d_in[1];
  const float* bq = (const float*)d_in[2];
  const float* Wk = (const float*)d_in[3];
  const float* bk = (const float*)d_in[4];
  const float* Wv = (const float*)d_in[5];
  const float* bv = (const float*)d_in[6];
  const float* Wo = (const float*)d_in[7];
  const float* bo = (const float*)d_in[8];
  float* Out = (float*)d_out;

  // ws layout: Q bf16 [128][2048][128] | ktv fp32 [128][4][32][32] | ksum fp32 [128][128]
  const size_t Q_BYTES    = (size_t)128 * 2048 * 128 * 2;        // 64 MiB
  const size_t KTV_BYTES  = (size_t)128 * 4 * 32 * 32 * 4;       // 2 MiB
  const size_t KSUM_BYTES = (size_t)128 * 128 * 4;               // 64 KiB
  __bf16* Qws   = (__bf16*)d_ws;
  float* ktvWs  = (float*)((char*)d_ws + Q_BYTES);
  float* ksumWs = (float*)((char*)d_ws + Q_BYTES + KTV_BYTES);

  hipMemsetAsync((char*)d_ws + Q_BYTES, 0, KTV_BYTES + KSUM_BYTES, stream);

  qkv_ktv_kernel<<<dim3(512), dim3(256), 0, stream>>>(
      X, Wq, bq, Wk, bk, Wv, bv, Qws, ktvWs, ksumWs);
  attn_out_kernel<<<dim3(512), dim3(256), 0, stream>>>(
      Qws, ktvWs, ksumWs, Wo, bo, Out);
}